// Round 15
// baseline (115.221 us; speedup 1.0000x reference)
//
#include <hip/hip_runtime.h>

typedef short v8s __attribute__((ext_vector_type(8)));
typedef short v4s __attribute__((ext_vector_type(4)));
typedef float v4f __attribute__((ext_vector_type(4)));
typedef int   v4i __attribute__((ext_vector_type(4)));

constexpr int Bb = 2, S = 2048, D = 1024, H = 16;
constexpr int M = Bb * S;   // 4096

#define DEV __device__ __forceinline__

DEV short f2bf(float f){
  unsigned u = __builtin_bit_cast(unsigned, f);
  u = (u + 0x7FFF + ((u >> 16) & 1)) >> 16;
  return (short)u;
}

DEV int swz(int r){ return (r ^ (r >> 2)) & 7; }

DEV int cvtpk(float lo, float hi){
  int r;
  asm("v_cvt_pk_bf16_f32 %0, %1, %2" : "=v"(r) : "v"(lo), "v"(hi));
  return r;
}

DEV float max3f(float a, float b, float c){
  float r;
  asm("v_max3_f32 %0, %1, %2, %3" : "=v"(r) : "v"(a), "v"(b), "v"(c));
  return r;
}

#define EXP2 exp2f

#define GLDS(gp, lp) __builtin_amdgcn_global_load_lds( \
    (const __attribute__((address_space(1))) void*)(gp), \
    (__attribute__((address_space(3))) void*)(lp), 16, 0, 0)

// ---------------- fused prep: x/xtb bf16 conversion + 4 weight conversions ----------------
struct PrepArgs {
  const float* x; const float* tg; const float* Wt; const float* bt;
  const float* Ws0; const float* Ws1; const float* Ws2; const float* Ws3;
  short* Wd0; short* Wd1; short* Wd2; short* Wd3;
  short* xb; short* xtb;
};
__global__ void prep_all(PrepArgs a){
  const int bx = blockIdx.x;
  if (bx < 4096){
    int i = bx * 256 + threadIdx.x;
    int row = i >> 8;
    int c4  = i & 255;
    float4 xv = reinterpret_cast<const float4*>(a.x)[i];
    float4 wv = reinterpret_cast<const float4*>(a.Wt)[c4];
    float4 bv = reinterpret_cast<const float4*>(a.bt)[c4];
    float g = a.tg[row];
    float xs[4] = {xv.x, xv.y, xv.z, xv.w};
    float ws[4] = {wv.x, wv.y, wv.z, wv.w};
    float bs[4] = {bv.x, bv.y, bv.z, bv.w};
    v4s p, q;
    #pragma unroll
    for (int e = 0; e < 4; ++e){
      p[e] = f2bf(xs[e]);
      q[e] = f2bf(xs[e] + g * ws[e] + bs[e]);
    }
    *reinterpret_cast<v4s*>(&a.xb[(size_t)i * 4])  = p;
    *reinterpret_cast<v4s*>(&a.xtb[(size_t)i * 4]) = q;
  } else {
    const int bi = bx - 4096;
    const int widx = bi >> 10;
    const float* src = widx == 0 ? a.Ws0 : widx == 1 ? a.Ws1 : widx == 2 ? a.Ws2 : a.Ws3;
    short* dst = widx == 0 ? a.Wd0 : widx == 1 ? a.Wd1 : widx == 2 ? a.Wd2 : a.Wd3;
    int i = (bi & 1023) * 256 + threadIdx.x;
    float4 v = reinterpret_cast<const float4*>(src)[i];
    v4s o; o[0] = f2bf(v.x); o[1] = f2bf(v.y); o[2] = f2bf(v.z); o[3] = f2bf(v.w);
    *reinterpret_cast<v4s*>(&dst[(size_t)i * 4]) = o;
  }
}

// ---------------- GEMM core 128x128 (MODE 0: bias[col]; MODE 1: bias[row];
// MODE 2: f32 out, bias[col]) ----------------------------------------------------
// BK=64, XOR-swizzled LDS, double-buffered staging, one barrier per K-step.
// LDS allocated by the CALLING KERNEL (64 KB) and passed in (R9 lesson: local
// __shared__ here duplicates per template instantiation -> 128 KB, occupancy 10%).
template<int MODE>
DEV void gemm_core(short* lds,
                   const short* __restrict__ A, const short* __restrict__ Bw,
                   const float* __restrict__ bias, float alpha, void* __restrict__ Cout,
                   int ldc, int m0, int n0){
  short* As = lds;                     // [2][128*64]
  short* Bs = lds + 2 * 128 * 64;      // [2][128*64]
  const int t = threadIdx.x;
  const int w = t >> 6, l = t & 63;
  const int wm = (w >> 1) * 64, wn = (w & 1) * 64;

  v4f acc[4][4] = {};

  auto stage = [&](int kt, int buf){
    const int k0 = kt * 64;
    #pragma unroll
    for (int j = 0; j < 4; ++j){
      const int cix = j * 256 + t;
      const int row = cix >> 3;
      const int c   = (cix & 7) ^ swz(row);
      GLDS(A  + (size_t)(m0 + row) * D + k0 + c * 8, As + buf * 8192 + cix * 8);
      GLDS(Bw + (size_t)(n0 + row) * D + k0 + c * 8, Bs + buf * 8192 + cix * 8);
    }
  };

  stage(0, 0);
  for (int kt = 0; kt < 16; ++kt){
    const int cur = kt & 1;
    __syncthreads();
    if (kt < 15) stage(kt + 1, cur ^ 1);
    #pragma unroll
    for (int kk = 0; kk < 2; ++kk){
      v8s af[4], bfr[4];
      #pragma unroll
      for (int mi = 0; mi < 4; ++mi){
        const int R = wm + mi * 16 + (l & 15);
        af[mi] = *reinterpret_cast<const v8s*>(&As[cur * 8192 + R * 64 + (((kk * 4 + (l >> 4)) ^ swz(R)) * 8)]);
      }
      #pragma unroll
      for (int ni = 0; ni < 4; ++ni){
        const int R = wn + ni * 16 + (l & 15);
        bfr[ni] = *reinterpret_cast<const v8s*>(&Bs[cur * 8192 + R * 64 + (((kk * 4 + (l >> 4)) ^ swz(R)) * 8)]);
      }
      __builtin_amdgcn_s_setprio(1);
      #pragma unroll
      for (int mi = 0; mi < 4; ++mi)
        #pragma unroll
        for (int ni = 0; ni < 4; ++ni)
          acc[mi][ni] = __builtin_amdgcn_mfma_f32_16x16x32_bf16(af[mi], bfr[ni], acc[mi][ni], 0, 0, 0);
      __builtin_amdgcn_s_setprio(0);
    }
  }

  #pragma unroll
  for (int mi = 0; mi < 4; ++mi){
    const int row = m0 + wm + mi * 16 + (l >> 4) * 4;
    #pragma unroll
    for (int ni = 0; ni < 4; ++ni){
      const int col = n0 + wn + ni * 16 + (l & 15);
      const float bcol = (MODE == 1) ? 0.f : bias[col];
      #pragma unroll
      for (int r = 0; r < 4; ++r){
        float bsel = (MODE == 1) ? bias[row + r] : bcol;
        float val = (acc[mi][ni][r] + bsel) * alpha;
        if (MODE == 2) reinterpret_cast<float*>(Cout)[(size_t)(row + r) * ldc + col] = val;
        else           reinterpret_cast<short*>(Cout)[(size_t)(row + r) * ldc + col] = f2bf(val);
      }
    }
  }
}

template<int MODE>
__global__ __launch_bounds__(256, 2)
void gemm_bt(const short* __restrict__ A, const short* __restrict__ Bw,
             const float* __restrict__ bias, float alpha, void* __restrict__ Cout, int ldc){
  __shared__ short lds[4 * 128 * 64];
  gemm_core<MODE>(lds, A, Bw, bias, alpha, Cout, ldc, blockIdx.x * 128, blockIdx.y * 128);
}

// fused Q+K+V^T projections: 768 blocks = 1.5 occupancy-rounds at 2/CU.
__global__ __launch_bounds__(256, 2)
void gemm_qkv(const short* __restrict__ xtb, const short* __restrict__ xb,
              const short* __restrict__ Wqb, const short* __restrict__ Wkb,
              const short* __restrict__ Wvb,
              const float* __restrict__ bq, const float* __restrict__ bk,
              const float* __restrict__ bv, float qalpha,
              short* __restrict__ Qb, short* __restrict__ Kb, short* __restrict__ VTb){
  __shared__ short lds[4 * 128 * 64];
  const int id = blockIdx.x;
  if (id < 512){
    const int li = id;
    const int yq = li >> 5;            // 0..15
    const bool isK = yq >= 8;
    gemm_core<0>(lds, xtb, isK ? Wkb : Wqb, isK ? bk : bq, isK ? 1.0f : qalpha,
                 isK ? (void*)Kb : (void*)Qb, D, (li & 31) * 128, (yq & 7) * 128);
  } else {
    const int li = id - 512;           // 0..255
    gemm_core<1>(lds, Wvb, xb, bv, 1.0f, VTb, M, (li & 7) * 128, (li >> 3) * 128);
  }
}

// ---------------- causal flash attention: 128-row q-tiles, 32 q-rows/wave ----------------
// R14 post-mortem: attn is LDS-READ-BW bound (64 KB frag reads per 64-row tile-iter).
// Fix: 4 waves x 32 q-rows (mi=0/1 statically-unrolled dual fragments, R3-proven) —
// K/V fragment loads shared across both mi accumulators -> LDS reads per q-row HALVE
// (36 MFMA per 16 ds_read_b128 vs 18). Block-iters also halve (8704 vs 16896).
// grid (bh=32, y=16) = 512 blocks = 2/CU; qx = (y<8)?15-y:y-8 pairs y,y+8 on one CU
// -> constant 34 staged iters/CU. nkt = 2qx+2. Waves skip fully-masked tiles.
// Skeleton: R13-proven depth-1, vmcnt(0)+s_barrier. XCD = id%8 = bh%8 L2 pinning.
// QK^T = mfma(K,Q) -> S^T with rho-permuted kv rows: lane's 16 P values per mi are
// exactly the PV B-fragment. Softmax: defer-max THR=8; row-sum via ones-A MFMA.
__global__ __launch_bounds__(256, 2)
void attn_kernel(const short* __restrict__ Q, const short* __restrict__ K,
                 const short* __restrict__ VT, const int* __restrict__ maskp,
                 short* __restrict__ O){
  __shared__ short Ks[2][64 * 64];
  __shared__ short Vs[2][64 * 64];     // V^T tile: rows = d, cols = kv
  __shared__ int mflag;
  const int t = threadIdx.x, w = t >> 6, l = t & 63;
  const int g = l >> 4, q16 = l & 15;
  const int bh = blockIdx.x, b = bh >> 4, h = bh & 15;
  const int yy = (int)blockIdx.y;
  const int qx = (yy < 8) ? 15 - yy : yy - 8;
  const int q0 = qx * 128;
  const int qw = q0 + w * 32;          // wave's first q-row (32 rows per wave)
  const int nkt = 2 * qx + 2;

  // ---- mask precheck over [0, nkt*64) ----
  if (t == 0) mflag = 1;
  __syncthreads();
  {
    bool ok = true;
    const int tot = nkt * 64;
    for (int i = t * 4; i < tot; i += 1024){
      v4i mm = *reinterpret_cast<const v4i*>(&maskp[b * S + i]);
      ok = ok && (mm[0] != 0) && (mm[1] != 0) && (mm[2] != 0) && (mm[3] != 0);
    }
    if (!__all(ok)) mflag = 0;   // benign race: all writers store 0
  }
  __syncthreads();
  const bool ALLV = (mflag != 0);

  v8s qf[2][2];                        // [mi][kc]
  #pragma unroll
  for (int mi = 0; mi < 2; ++mi)
    #pragma unroll
    for (int kc = 0; kc < 2; ++kc)
      qf[mi][kc] = *reinterpret_cast<const v8s*>(
          &Q[(size_t)(b * S + qw + mi * 16 + q16) * D + h * 64 + kc * 32 + g * 8]);

  // precomputed swizzled LDS element offsets (loop-invariant, stay in VGPRs)
  int kOff[4][2], vOff[4][2];
  #pragma unroll
  for (int nt = 0; nt < 4; ++nt){
    const int R = 32 * (nt >> 1) + 8 * (q16 >> 2) + 4 * (nt & 1) + (l & 3);
    #pragma unroll
    for (int kc = 0; kc < 2; ++kc)
      kOff[nt][kc] = R * 64 + (((kc * 4 + g) ^ swz(R)) * 8);
  }
  #pragma unroll
  for (int dt = 0; dt < 4; ++dt){
    const int R = dt * 16 + q16;
    #pragma unroll
    for (int kc = 0; kc < 2; ++kc)
      vOff[dt][kc] = R * 64 + (((kc * 4 + g) ^ swz(R)) * 8);
  }

  v4f accOT[2][4] = {};                // [mi]: O^T col=q(lane), rows=d
  v4f accL[2] = {};                    // [mi] row-sum accumulators
  float mrow[2] = {-1e30f, -1e30f};

  const v4i onesW = {0x3F803F80, 0x3F803F80, 0x3F803F80, 0x3F803F80};
  const v8s onesv = __builtin_bit_cast(v8s, onesW);   // bf16 1.0 x8

  auto stage = [&](int kt){
    const int buf = kt & 1;
    const int kv0 = kt * 64;
    #pragma unroll
    for (int j = 0; j < 2; ++j){
      const int cix = j * 256 + t;
      const int row = cix >> 3;
      const int c   = (cix & 7) ^ swz(row);
      GLDS(K  + (size_t)(b * S + kv0 + row) * D + h * 64 + c * 8, &Ks[buf][cix * 8]);
      GLDS(VT + (size_t)(h * 64 + row) * M + b * S + kv0 + c * 8, &Vs[buf][cix * 8]);
    }
  };

  // QK^T for both mi with shared K fragments
  auto qk2 = [&](const short* kb, v4f (&sc)[2][4]){
    __builtin_amdgcn_s_setprio(1);
    #pragma unroll
    for (int nt = 0; nt < 4; ++nt)
      #pragma unroll
      for (int kc = 0; kc < 2; ++kc){
        v8s kf = *reinterpret_cast<const v8s*>(kb + kOff[nt][kc]);
        sc[0][nt] = __builtin_amdgcn_mfma_f32_16x16x32_bf16(kf, qf[0][kc], sc[0][nt], 0, 0, 0);
        sc[1][nt] = __builtin_amdgcn_mfma_f32_16x16x32_bf16(kf, qf[1][kc], sc[1][nt], 0, 0, 0);
      }
    __builtin_amdgcn_s_setprio(0);
  };

  // softmax (defer-max) + pack for one mi; p consumed immediately
  auto softmax_pack = [&](float (&p)[16], int mi, int (&pb)[2][4]){
    float t0 = max3f(p[0], p[1], p[2]);
    float t1 = max3f(p[3], p[4], p[5]);
    float t2 = max3f(p[6], p[7], p[8]);
    float t3 = max3f(p[9], p[10], p[11]);
    float t4 = max3f(p[12], p[13], p[14]);
    float tm = max3f(max3f(t0, t1, t2), t3, fmaxf(t4, p[15]));
    if (!__all(tm <= mrow[mi] + 8.0f)){
      float tmax = fmaxf(tm, __shfl_xor(tm, 16));
      tmax = fmaxf(tmax, __shfl_xor(tmax, 32));
      const float mnew = fmaxf(mrow[mi], tmax);
      const float resc = EXP2(mrow[mi] - mnew);
      #pragma unroll
      for (int dt = 0; dt < 4; ++dt) accOT[mi][dt] *= resc;
      accL[mi] *= resc;
      mrow[mi] = mnew;
    }
    #pragma unroll
    for (int j = 0; j < 16; ++j) p[j] = EXP2(p[j] - mrow[mi]);
    #pragma unroll
    for (int kc = 0; kc < 2; ++kc)
      #pragma unroll
      for (int s = 0; s < 4; ++s){
        const int base = (2 * kc + (s >> 1)) * 4 + (s & 1) * 2;
        pb[kc][s] = cvtpk(p[base], p[base + 1]);
      }
  };

  // PV for both mi with shared V fragments
  auto pv2 = [&](const short* vb, int (&pb0)[2][4], int (&pb1)[2][4]){
    __builtin_amdgcn_s_setprio(1);
    #pragma unroll
    for (int kc = 0; kc < 2; ++kc){
      v4i t0 = {pb0[kc][0], pb0[kc][1], pb0[kc][2], pb0[kc][3]};
      v4i t1 = {pb1[kc][0], pb1[kc][1], pb1[kc][2], pb1[kc][3]};
      v8s pv0 = __builtin_bit_cast(v8s, t0);
      v8s pv1 = __builtin_bit_cast(v8s, t1);
      accL[0] = __builtin_amdgcn_mfma_f32_16x16x32_bf16(onesv, pv0, accL[0], 0, 0, 0);
      accL[1] = __builtin_amdgcn_mfma_f32_16x16x32_bf16(onesv, pv1, accL[1], 0, 0, 0);
      #pragma unroll
      for (int dt = 0; dt < 4; ++dt){
        v8s vf = *reinterpret_cast<const v8s*>(vb + vOff[dt][kc]);
        accOT[0][dt] = __builtin_amdgcn_mfma_f32_16x16x32_bf16(vf, pv0, accOT[0][dt], 0, 0, 0);
        accOT[1][dt] = __builtin_amdgcn_mfma_f32_16x16x32_bf16(vf, pv1, accOT[1][dt], 0, 0, 0);
      }
    }
    __builtin_amdgcn_s_setprio(0);
  };

  stage(0);

  if (ALLV){
    // fast path: no in-loop vmem except staging
    for (int kt = 0; kt < nkt; ++kt){
      asm volatile("s_waitcnt vmcnt(0)" ::: "memory");
      __builtin_amdgcn_s_barrier();
      if (kt + 1 < nkt) stage(kt + 1);

      const int kv0 = kt * 64;
      if (kv0 > qw + 31) continue;     // tile fully above this wave's diagonal

      const short* kb = Ks[kt & 1];
      const short* vb = Vs[kt & 1];

      v4f sc[2][4] = {};
      qk2(kb, sc);

      int pb0[2][4], pb1[2][4];
      if (kv0 + 63 <= qw){
        // interior tile: straight copy for both mi
        #pragma unroll
        for (int mi = 0; mi < 2; ++mi){
          float p[16];
          #pragma unroll
          for (int j = 0; j < 16; ++j) p[j] = sc[mi][j >> 2][j & 3];
          softmax_pack(p, mi, mi == 0 ? pb0 : pb1);
        }
      } else {
        // diagonal region: causal compare per mi
        #pragma unroll
        for (int mi = 0; mi < 2; ++mi){
          const int qg = qw + mi * 16 + q16;
          float p[16];
          #pragma unroll
          for (int nt = 0; nt < 4; ++nt)
            #pragma unroll
            for (int r = 0; r < 4; ++r){
              const int kvg = kv0 + 32 * (nt >> 1) + 8 * g + 4 * (nt & 1) + r;
              p[nt * 4 + r] = (kvg > qg) ? -1e30f : sc[mi][nt][r];
            }
          softmax_pack(p, mi, mi == 0 ? pb0 : pb1);
        }
      }
      pv2(vb, pb0, pb1);
    }
  } else {
    // slow path: padding mask everywhere
    for (int kt = 0; kt < nkt; ++kt){
      asm volatile("s_waitcnt vmcnt(0)" ::: "memory");
      __builtin_amdgcn_s_barrier();
      if (kt + 1 < nkt) stage(kt + 1);

      const int kv0 = kt * 64;
      if (kv0 > qw + 31) continue;

      const short* kb = Ks[kt & 1];
      const short* vb = Vs[kt & 1];

      v4i mq[4];
      #pragma unroll
      for (int nt = 0; nt < 4; ++nt)
        mq[nt] = *reinterpret_cast<const v4i*>(
            &maskp[b * S + kv0 + 32 * (nt >> 1) + 8 * g + 4 * (nt & 1)]);

      v4f sc[2][4] = {};
      qk2(kb, sc);

      int pb0[2][4], pb1[2][4];
      #pragma unroll
      for (int mi = 0; mi < 2; ++mi){
        const int qg = qw + mi * 16 + q16;
        float p[16];
        #pragma unroll
        for (int nt = 0; nt < 4; ++nt)
          #pragma unroll
          for (int r = 0; r < 4; ++r){
            const int kvg = kv0 + 32 * (nt >> 1) + 8 * g + 4 * (nt & 1) + r;
            const int kvx = (mq[nt][r] != 0) ? kvg : 0x7fffffff;
            p[nt * 4 + r] = (kvx > qg) ? -1e30f : sc[mi][nt][r];
          }
        softmax_pack(p, mi, mi == 0 ? pb0 : pb1);
      }
      pv2(vb, pb0, pb1);
    }
  }

  // epilogue: O[q][d] = accOT^T / l for both mi
  #pragma unroll
  for (int mi = 0; mi < 2; ++mi){
    const float inv = 1.0f / accL[mi][0];
    #pragma unroll
    for (int dt = 0; dt < 4; ++dt){
      v4s o4;
      #pragma unroll
      for (int r = 0; r < 4; ++r) o4[r] = f2bf(accOT[mi][dt][r] * inv);
      *reinterpret_cast<v4s*>(
          &O[(size_t)(b * S + qw + mi * 16 + q16) * D + h * 64 + dt * 16 + g * 4]) = o4;
    }
  }
}

extern "C" void kernel_launch(void* const* d_in, const int* in_sizes, int n_in,
                              void* d_out, int out_size, void* d_ws, size_t ws_size,
                              hipStream_t stream){
  const float* x   = (const float*)d_in[0];
  const float* tg  = (const float*)d_in[1];
  const int*   msk = (const int*)d_in[2];
  const float* Wq  = (const float*)d_in[3];
  const float* bq  = (const float*)d_in[4];
  const float* Wk  = (const float*)d_in[5];
  const float* bk  = (const float*)d_in[6];
  const float* Wv  = (const float*)d_in[7];
  const float* bv  = (const float*)d_in[8];
  const float* Wo  = (const float*)d_in[9];
  const float* bo  = (const float*)d_in[10];
  const float* Wt  = (const float*)d_in[11];
  const float* bt  = (const float*)d_in[12];

  char* ws = (char*)d_ws;
  const size_t MB = 1u << 20;
  short* xb  = (short*)(ws);             // 8 MB
  short* xtb = (short*)(ws + 8 * MB);    // 8 MB
  short* Wqb = (short*)(ws + 16 * MB);   // 2 MB each
  short* Wkb = (short*)(ws + 18 * MB);
  short* Wvb = (short*)(ws + 20 * MB);
  short* Wob = (short*)(ws + 22 * MB);
  short* Qb  = (short*)(ws + 24 * MB);   // 8 MB
  short* Kb  = (short*)(ws + 32 * MB);
  short* VTb = (short*)(ws + 40 * MB);   // V^T [1024][4096]
  short* Ab  = (short*)(ws + 48 * MB);   // 8 MB -> 56 MB total

  PrepArgs pa;
  pa.x = x; pa.tg = tg; pa.Wt = Wt; pa.bt = bt;
  pa.Ws0 = Wq; pa.Ws1 = Wk; pa.Ws2 = Wv; pa.Ws3 = Wo;
  pa.Wd0 = Wqb; pa.Wd1 = Wkb; pa.Wd2 = Wvb; pa.Wd3 = Wob;
  pa.xb = xb; pa.xtb = xtb;
  prep_all<<<8192, 256, 0, stream>>>(pa);

  const float qalpha = 0.125f * 1.4426950408889634f;   // 1/sqrt(64) * log2(e)
  gemm_qkv<<<768, 256, 0, stream>>>(xtb, xb, Wqb, Wkb, Wvb, bq, bk, bv, qalpha,
                                    Qb, Kb, VTb);

  attn_kernel<<<dim3(Bb * H, 16), 256, 0, stream>>>(Qb, Kb, VTb, msk, Ab);

  gemm_bt<2><<<dim3(M / 128, D / 128), 256, 0, stream>>>(Ab, Wob, bo, 1.0f, (float*)d_out, D);
}

// Round 16
// 103.830 us; speedup vs baseline: 1.1097x; 1.1097x over previous
//
#include <hip/hip_runtime.h>

typedef short v8s __attribute__((ext_vector_type(8)));
typedef short v4s __attribute__((ext_vector_type(4)));
typedef float v4f __attribute__((ext_vector_type(4)));
typedef int   v4i __attribute__((ext_vector_type(4)));

constexpr int Bb = 2, S = 2048, D = 1024, H = 16;
constexpr int M = Bb * S;   // 4096

#define DEV __device__ __forceinline__

DEV short f2bf(float f){
  unsigned u = __builtin_bit_cast(unsigned, f);
  u = (u + 0x7FFF + ((u >> 16) & 1)) >> 16;
  return (short)u;
}

DEV int swz(int r){ return (r ^ (r >> 2)) & 7; }

DEV int cvtpk(float lo, float hi){
  int r;
  asm("v_cvt_pk_bf16_f32 %0, %1, %2" : "=v"(r) : "v"(lo), "v"(hi));
  return r;
}

DEV float max3f(float a, float b, float c){
  float r;
  asm("v_max3_f32 %0, %1, %2, %3" : "=v"(r) : "v"(a), "v"(b), "v"(c));
  return r;
}

#define EXP2 exp2f

#define GLDS(gp, lp) __builtin_amdgcn_global_load_lds( \
    (const __attribute__((address_space(1))) void*)(gp), \
    (__attribute__((address_space(3))) void*)(lp), 16, 0, 0)

// ---------------- fused prep: x/xtb bf16 conversion + 4 weight conversions ----------------
struct PrepArgs {
  const float* x; const float* tg; const float* Wt; const float* bt;
  const float* Ws0; const float* Ws1; const float* Ws2; const float* Ws3;
  short* Wd0; short* Wd1; short* Wd2; short* Wd3;
  short* xb; short* xtb;
};
__global__ void prep_all(PrepArgs a){
  const int bx = blockIdx.x;
  if (bx < 4096){
    int i = bx * 256 + threadIdx.x;
    int row = i >> 8;
    int c4  = i & 255;
    float4 xv = reinterpret_cast<const float4*>(a.x)[i];
    float4 wv = reinterpret_cast<const float4*>(a.Wt)[c4];
    float4 bv = reinterpret_cast<const float4*>(a.bt)[c4];
    float g = a.tg[row];
    float xs[4] = {xv.x, xv.y, xv.z, xv.w};
    float ws[4] = {wv.x, wv.y, wv.z, wv.w};
    float bs[4] = {bv.x, bv.y, bv.z, bv.w};
    v4s p, q;
    #pragma unroll
    for (int e = 0; e < 4; ++e){
      p[e] = f2bf(xs[e]);
      q[e] = f2bf(xs[e] + g * ws[e] + bs[e]);
    }
    *reinterpret_cast<v4s*>(&a.xb[(size_t)i * 4])  = p;
    *reinterpret_cast<v4s*>(&a.xtb[(size_t)i * 4]) = q;
  } else {
    const int bi = bx - 4096;
    const int widx = bi >> 10;
    const float* src = widx == 0 ? a.Ws0 : widx == 1 ? a.Ws1 : widx == 2 ? a.Ws2 : a.Ws3;
    short* dst = widx == 0 ? a.Wd0 : widx == 1 ? a.Wd1 : widx == 2 ? a.Wd2 : a.Wd3;
    int i = (bi & 1023) * 256 + threadIdx.x;
    float4 v = reinterpret_cast<const float4*>(src)[i];
    v4s o; o[0] = f2bf(v.x); o[1] = f2bf(v.y); o[2] = f2bf(v.z); o[3] = f2bf(v.w);
    *reinterpret_cast<v4s*>(&dst[(size_t)i * 4]) = o;
  }
}

// ---------------- GEMM core 128x128 (MODE 0: bias[col]; MODE 1: bias[row];
// MODE 2: f32 out, bias[col]) ----------------------------------------------------
// BK=64, XOR-swizzled LDS, double-buffered staging, one barrier per K-step.
// LDS is allocated by the CALLING KERNEL (64 KB) and passed in — declaring it here
// would duplicate it per template instantiation (R9: 128 KB/block, occupancy 10%).
template<int MODE>
DEV void gemm_core(short* lds,
                   const short* __restrict__ A, const short* __restrict__ Bw,
                   const float* __restrict__ bias, float alpha, void* __restrict__ Cout,
                   int ldc, int m0, int n0){
  short* As = lds;                     // [2][128*64]
  short* Bs = lds + 2 * 128 * 64;      // [2][128*64]
  const int t = threadIdx.x;
  const int w = t >> 6, l = t & 63;
  const int wm = (w >> 1) * 64, wn = (w & 1) * 64;

  v4f acc[4][4] = {};

  auto stage = [&](int kt, int buf){
    const int k0 = kt * 64;
    #pragma unroll
    for (int j = 0; j < 4; ++j){
      const int cix = j * 256 + t;
      const int row = cix >> 3;
      const int c   = (cix & 7) ^ swz(row);
      GLDS(A  + (size_t)(m0 + row) * D + k0 + c * 8, As + buf * 8192 + cix * 8);
      GLDS(Bw + (size_t)(n0 + row) * D + k0 + c * 8, Bs + buf * 8192 + cix * 8);
    }
  };

  stage(0, 0);
  for (int kt = 0; kt < 16; ++kt){
    const int cur = kt & 1;
    __syncthreads();
    if (kt < 15) stage(kt + 1, cur ^ 1);
    #pragma unroll
    for (int kk = 0; kk < 2; ++kk){
      v8s af[4], bfr[4];
      #pragma unroll
      for (int mi = 0; mi < 4; ++mi){
        const int R = wm + mi * 16 + (l & 15);
        af[mi] = *reinterpret_cast<const v8s*>(&As[cur * 8192 + R * 64 + (((kk * 4 + (l >> 4)) ^ swz(R)) * 8)]);
      }
      #pragma unroll
      for (int ni = 0; ni < 4; ++ni){
        const int R = wn + ni * 16 + (l & 15);
        bfr[ni] = *reinterpret_cast<const v8s*>(&Bs[cur * 8192 + R * 64 + (((kk * 4 + (l >> 4)) ^ swz(R)) * 8)]);
      }
      __builtin_amdgcn_s_setprio(1);
      #pragma unroll
      for (int mi = 0; mi < 4; ++mi)
        #pragma unroll
        for (int ni = 0; ni < 4; ++ni)
          acc[mi][ni] = __builtin_amdgcn_mfma_f32_16x16x32_bf16(af[mi], bfr[ni], acc[mi][ni], 0, 0, 0);
      __builtin_amdgcn_s_setprio(0);
    }
  }

  #pragma unroll
  for (int mi = 0; mi < 4; ++mi){
    const int row = m0 + wm + mi * 16 + (l >> 4) * 4;
    #pragma unroll
    for (int ni = 0; ni < 4; ++ni){
      const int col = n0 + wn + ni * 16 + (l & 15);
      const float bcol = (MODE == 1) ? 0.f : bias[col];
      #pragma unroll
      for (int r = 0; r < 4; ++r){
        float bsel = (MODE == 1) ? bias[row + r] : bcol;
        float val = (acc[mi][ni][r] + bsel) * alpha;
        if (MODE == 2) reinterpret_cast<float*>(Cout)[(size_t)(row + r) * ldc + col] = val;
        else           reinterpret_cast<short*>(Cout)[(size_t)(row + r) * ldc + col] = f2bf(val);
      }
    }
  }
}

template<int MODE>
__global__ __launch_bounds__(256, 2)
void gemm_bt(const short* __restrict__ A, const short* __restrict__ Bw,
             const float* __restrict__ bias, float alpha, void* __restrict__ Cout, int ldc){
  __shared__ short lds[4 * 128 * 64];
  gemm_core<MODE>(lds, A, Bw, bias, alpha, Cout, ldc, blockIdx.x * 128, blockIdx.y * 128);
}

// fused Q+K+V^T projections: 768 blocks = 1.5 occupancy-rounds at 2/CU.
// Single 64 KB LDS buffer shared by both gemm_core instantiations.
__global__ __launch_bounds__(256, 2)
void gemm_qkv(const short* __restrict__ xtb, const short* __restrict__ xb,
              const short* __restrict__ Wqb, const short* __restrict__ Wkb,
              const short* __restrict__ Wvb,
              const float* __restrict__ bq, const float* __restrict__ bk,
              const float* __restrict__ bv, float qalpha,
              short* __restrict__ Qb, short* __restrict__ Kb, short* __restrict__ VTb){
  __shared__ short lds[4 * 128 * 64];
  const int id = blockIdx.x;
  if (id < 512){
    const int li = id;
    const int yq = li >> 5;            // 0..15
    const bool isK = yq >= 8;
    gemm_core<0>(lds, xtb, isK ? Wkb : Wqb, isK ? bk : bq, isK ? 1.0f : qalpha,
                 isK ? (void*)Kb : (void*)Qb, D, (li & 31) * 128, (yq & 7) * 128);
  } else {
    const int li = id - 512;           // 0..255
    // V^T: rows = feature n (A=Wv), cols = token m (B=xb), bias per row
    gemm_core<1>(lds, Wvb, xb, bv, 1.0f, VTb, M, (li & 7) * 128, (li >> 3) * 128);
  }
}

// ---------------- causal flash attention (R10-proven kernel, byte-exact) ----------------
// grid: (bh=32, rank=32) = 1024 blocks; 2 LDS buffers (32 KB) -> 4 blocks/CU.
// qx = per-octant (31-y, y-8, 39-y, y-16): bijective, each CU's four ranks get qx
// summing exactly 62 -> 66 tiles/CU. XCD = id%8 = bh%8 pins each head's KV stream
// to one L2 (FETCH 64->12 MB measured in R8). Depth-1 prefetch, vmcnt(0)+s_barrier.
// R8-R15 consolidated: 4 blocks/CU is the binding constraint (latency-bound serial
// chain); chain-split (R14), bigger tiles (R15), counted-vmcnt+pairing (R11/12) all
// neutral-to-worse. QK^T = mfma(K,Q) -> S^T with rho-permuted kv rows: lane's 16 P
// values are exactly the PV B-fragment. Softmax: defer-max THR=8; ones-A MFMA l-sum.
__global__ __launch_bounds__(256, 4)
void attn_kernel(const short* __restrict__ Q, const short* __restrict__ K,
                 const short* __restrict__ VT, const int* __restrict__ maskp,
                 short* __restrict__ O){
  __shared__ short Ks[2][64 * 64];
  __shared__ short Vs[2][64 * 64];     // V^T tile: rows = d, cols = kv
  __shared__ int mflag;
  const int t = threadIdx.x, w = t >> 6, l = t & 63;
  const int g = l >> 4, q16 = l & 15;
  const int bh = blockIdx.x, b = bh >> 4, h = bh & 15;
  const int yy = (int)blockIdx.y;
  const int qx = (yy < 8) ? 31 - yy : (yy < 16) ? yy - 8 : (yy < 24) ? 39 - yy : yy - 16;
  const int q0 = qx * 64;
  const int qw = q0 + w * 16;          // wave's 16 q-rows
  const int qg = qw + q16;             // this lane's q row
  const int nkt = qx + 1;

  // ---- mask precheck over [0, nkt*64) ----
  if (t == 0) mflag = 1;
  __syncthreads();
  {
    bool ok = true;
    const int tot = nkt * 64;
    for (int i = t * 4; i < tot; i += 1024){
      v4i mm = *reinterpret_cast<const v4i*>(&maskp[b * S + i]);
      ok = ok && (mm[0] != 0) && (mm[1] != 0) && (mm[2] != 0) && (mm[3] != 0);
    }
    if (!__all(ok)) mflag = 0;   // benign race: all writers store 0
  }
  __syncthreads();
  const bool ALLV = (mflag != 0);

  v8s qf[2];
  #pragma unroll
  for (int kc = 0; kc < 2; ++kc)
    qf[kc] = *reinterpret_cast<const v8s*>(
        &Q[(size_t)(b * S + qg) * D + h * 64 + kc * 32 + g * 8]);

  // precomputed swizzled LDS element offsets (loop-invariant, stay in VGPRs)
  int kOff[4][2], vOff[4][2];
  #pragma unroll
  for (int nt = 0; nt < 4; ++nt){
    const int R = 32 * (nt >> 1) + 8 * (q16 >> 2) + 4 * (nt & 1) + (l & 3);
    #pragma unroll
    for (int kc = 0; kc < 2; ++kc)
      kOff[nt][kc] = R * 64 + (((kc * 4 + g) ^ swz(R)) * 8);
  }
  #pragma unroll
  for (int dt = 0; dt < 4; ++dt){
    const int R = dt * 16 + q16;
    #pragma unroll
    for (int kc = 0; kc < 2; ++kc)
      vOff[dt][kc] = R * 64 + (((kc * 4 + g) ^ swz(R)) * 8);
  }

  v4f accOT[4] = {};                   // O^T: col=q(lane), rows=d
  v4f accL = {};                       // row-sum accumulator
  float mrow = -1e30f;

  const v4i onesW = {0x3F803F80, 0x3F803F80, 0x3F803F80, 0x3F803F80};
  const v8s onesv = __builtin_bit_cast(v8s, onesW);   // bf16 1.0 x8

  auto stage = [&](int kt){
    const int buf = kt & 1;
    const int kv0 = kt * 64;
    #pragma unroll
    for (int j = 0; j < 2; ++j){
      const int cix = j * 256 + t;
      const int row = cix >> 3;
      const int c   = (cix & 7) ^ swz(row);
      GLDS(K  + (size_t)(b * S + kv0 + row) * D + h * 64 + c * 8, &Ks[buf][cix * 8]);
      GLDS(VT + (size_t)(h * 64 + row) * M + b * S + kv0 + c * 8, &Vs[buf][cix * 8]);
    }
  };

  auto softmax_pv = [&](float (&p)[16], const short* vb){
    float t0 = max3f(p[0], p[1], p[2]);
    float t1 = max3f(p[3], p[4], p[5]);
    float t2 = max3f(p[6], p[7], p[8]);
    float t3 = max3f(p[9], p[10], p[11]);
    float t4 = max3f(p[12], p[13], p[14]);
    float tm = max3f(max3f(t0, t1, t2), t3, fmaxf(t4, p[15]));
    if (!__all(tm <= mrow + 8.0f)){
      float tmax = fmaxf(tm, __shfl_xor(tm, 16));
      tmax = fmaxf(tmax, __shfl_xor(tmax, 32));
      const float mnew = fmaxf(mrow, tmax);
      const float resc = EXP2(mrow - mnew);
      #pragma unroll
      for (int dt = 0; dt < 4; ++dt) accOT[dt] *= resc;
      accL *= resc;
      mrow = mnew;
    }
    #pragma unroll
    for (int j = 0; j < 16; ++j) p[j] = EXP2(p[j] - mrow);

    int pb[2][4];
    #pragma unroll
    for (int kc = 0; kc < 2; ++kc)
      #pragma unroll
      for (int s = 0; s < 4; ++s){
        const int base = (2 * kc + (s >> 1)) * 4 + (s & 1) * 2;
        pb[kc][s] = cvtpk(p[base], p[base + 1]);
      }

    __builtin_amdgcn_s_setprio(1);
    #pragma unroll
    for (int kc = 0; kc < 2; ++kc){
      v4i tmp = {pb[kc][0], pb[kc][1], pb[kc][2], pb[kc][3]};
      v8s pbv = __builtin_bit_cast(v8s, tmp);
      accL = __builtin_amdgcn_mfma_f32_16x16x32_bf16(onesv, pbv, accL, 0, 0, 0);
      #pragma unroll
      for (int dt = 0; dt < 4; ++dt){
        v8s vf = *reinterpret_cast<const v8s*>(vb + vOff[dt][kc]);
        accOT[dt] = __builtin_amdgcn_mfma_f32_16x16x32_bf16(vf, pbv, accOT[dt], 0, 0, 0);
      }
    }
    __builtin_amdgcn_s_setprio(0);
  };

  auto qk = [&](const short* kb, v4f (&sc)[4]){
    __builtin_amdgcn_s_setprio(1);
    #pragma unroll
    for (int nt = 0; nt < 4; ++nt)
      #pragma unroll
      for (int kc = 0; kc < 2; ++kc){
        v8s kf = *reinterpret_cast<const v8s*>(kb + kOff[nt][kc]);
        sc[nt] = __builtin_amdgcn_mfma_f32_16x16x32_bf16(kf, qf[kc], sc[nt], 0, 0, 0);
      }
    __builtin_amdgcn_s_setprio(0);
  };

  stage(0);

  if (ALLV){
    // fast path: depth-1 pipeline, no in-loop vmem but staging
    for (int kt = 0; kt < nkt; ++kt){
      asm volatile("s_waitcnt vmcnt(0)" ::: "memory");
      __builtin_amdgcn_s_barrier();
      if (kt + 1 < nkt) stage(kt + 1);

      const short* kb = Ks[kt & 1];
      const short* vb = Vs[kt & 1];

      v4f sc[4] = {};
      qk(kb, sc);

      float p[16];
      if (kt < qx){
        #pragma unroll
        for (int j = 0; j < 16; ++j) p[j] = sc[j >> 2][j & 3];
      } else {
        const int kv0 = kt * 64;
        #pragma unroll
        for (int nt = 0; nt < 4; ++nt)
          #pragma unroll
          for (int r = 0; r < 4; ++r){
            const int kvg = kv0 + 32 * (nt >> 1) + 8 * g + 4 * (nt & 1) + r;
            p[nt * 4 + r] = (kvg > qg) ? -1e30f : sc[nt][r];
          }
      }
      softmax_pv(p, vb);
    }
  } else {
    // slow path: full-drain per tile + padding mask
    for (int kt = 0; kt < nkt; ++kt){
      asm volatile("s_waitcnt vmcnt(0)" ::: "memory");
      __builtin_amdgcn_s_barrier();
      if (kt + 1 < nkt) stage(kt + 1);

      const short* kb = Ks[kt & 1];
      const short* vb = Vs[kt & 1];
      const int kv0 = kt * 64;

      v4i mq[4];
      #pragma unroll
      for (int nt = 0; nt < 4; ++nt)
        mq[nt] = *reinterpret_cast<const v4i*>(
            &maskp[b * S + kv0 + 32 * (nt >> 1) + 8 * g + 4 * (nt & 1)]);

      v4f sc[4] = {};
      qk(kb, sc);

      float p[16];
      #pragma unroll
      for (int nt = 0; nt < 4; ++nt)
        #pragma unroll
        for (int r = 0; r < 4; ++r){
          const int kvg = kv0 + 32 * (nt >> 1) + 8 * g + 4 * (nt & 1) + r;
          const int kvx = (mq[nt][r] != 0) ? kvg : 0x7fffffff;
          p[nt * 4 + r] = (kvx > qg) ? -1e30f : sc[nt][r];
        }
      softmax_pv(p, vb);
    }
  }

  // epilogue: O[q][d] = accOT^T / l
  const float inv = 1.0f / accL[0];
  #pragma unroll
  for (int dt = 0; dt < 4; ++dt){
    v4s o4;
    #pragma unroll
    for (int r = 0; r < 4; ++r) o4[r] = f2bf(accOT[dt][r] * inv);
    *reinterpret_cast<v4s*>(
        &O[(size_t)(b * S + qg) * D + h * 64 + dt * 16 + g * 4]) = o4;
  }
}

extern "C" void kernel_launch(void* const* d_in, const int* in_sizes, int n_in,
                              void* d_out, int out_size, void* d_ws, size_t ws_size,
                              hipStream_t stream){
  const float* x   = (const float*)d_in[0];
  const float* tg  = (const float*)d_in[1];
  const int*   msk = (const int*)d_in[2];
  const float* Wq  = (const float*)d_in[3];
  const float* bq  = (const float*)d_in[4];
  const float* Wk  = (const float*)d_in[5];
  const float* bk  = (const float*)d_in[6];
  const float* Wv  = (const float*)d_in[7];
  const float* bv  = (const float*)d_in[8];
  const float* Wo  = (const float*)d_in[9];
  const float* bo  = (const float*)d_in[10];
  const float* Wt  = (const float*)d_in[11];
  const float* bt  = (const float*)d_in[12];

  char* ws = (char*)d_ws;
  const size_t MB = 1u << 20;
  short* xb  = (short*)(ws);             // 8 MB
  short* xtb = (short*)(ws + 8 * MB);    // 8 MB
  short* Wqb = (short*)(ws + 16 * MB);   // 2 MB each
  short* Wkb = (short*)(ws + 18 * MB);
  short* Wvb = (short*)(ws + 20 * MB);
  short* Wob = (short*)(ws + 22 * MB);
  short* Qb  = (short*)(ws + 24 * MB);   // 8 MB
  short* Kb  = (short*)(ws + 32 * MB);
  short* VTb = (short*)(ws + 40 * MB);   // V^T [1024][4096]
  short* Ab  = (short*)(ws + 48 * MB);   // 8 MB -> 56 MB total

  PrepArgs pa;
  pa.x = x; pa.tg = tg; pa.Wt = Wt; pa.bt = bt;
  pa.Ws0 = Wq; pa.Ws1 = Wk; pa.Ws2 = Wv; pa.Ws3 = Wo;
  pa.Wd0 = Wqb; pa.Wd1 = Wkb; pa.Wd2 = Wvb; pa.Wd3 = Wob;
  pa.xb = xb; pa.xtb = xtb;
  prep_all<<<8192, 256, 0, stream>>>(pa);

  const float qalpha = 0.125f * 1.4426950408889634f;   // 1/sqrt(64) * log2(e)
  gemm_qkv<<<768, 256, 0, stream>>>(xtb, xb, Wqb, Wkb, Wvb, bq, bk, bv, qalpha,
                                    Qb, Kb, VTb);

  attn_kernel<<<dim3(Bb * H, 32), 256, 0, stream>>>(Qb, Kb, VTb, msk, Ab);

  gemm_bt<2><<<dim3(M / 128, D / 128), 256, 0, stream>>>(Ab, Wob, bo, 1.0f, (float*)d_out, D);
}